// Round 6
// baseline (476.725 us; speedup 1.0000x reference)
//
#include <hip/hip_runtime.h>
#include <stdint.h>

typedef unsigned short u16;
typedef __attribute__((ext_vector_type(8))) short short8;   // 8 bf16 = 4 VGPRs (MFMA A/B frag)
typedef __attribute__((ext_vector_type(4))) float f32x4;    // MFMA C/D frag

#define LOG2E 1.4426950408889634f
#define NT 8192
#define DH 256

// ---- workspace layout (u16 element offsets) ----
// persistent across flash:
#define QH     0
#define KH     2097152
#define VTB    4194304          // V transposed: [256][8192]
#define OPARTB 6291456          // 8 x [8192][256] bf16 unnormalized partial O (32 MB)
// temps (dead after k_qkv; deliberately overlap OPARTB region):
#define XH0 6291456
#define XL0 8388608
#define XH1 10485760
#define XL1 12582912
#define XH2 14680064
#define XL2 16777216
#define WQH 18874368
#define WQL 18939904
#define WKH 19005440
#define WKL 19070976
#define WVH 19136512
#define WVL 19202048
// fp32 region (float element offsets), after OPARTB (byte 46,137,344):
#define MPART_F 11534336        // 8 x [8192] per-split softmax base m0
#define LPART_F 11599872        // 8 x [8192] per-split denom

__device__ __forceinline__ u16 f2bf(float f) {
  union { float f; uint32_t u; } c; c.f = f;
  uint32_t u = c.u;
  return (u16)((u + 0x7fffu + ((u >> 16) & 1)) >> 16);   // RNE
}
__device__ __forceinline__ u16 f2bf_hu(float f) {        // round-half-up: 2 VALU ops
  union { float f; uint32_t u; } c; c.f = f;
  return (u16)((c.u + 0x8000u) >> 16);
}
__device__ __forceinline__ float bf2f(u16 h) {
  union { uint32_t u; float f; } c; c.u = ((uint32_t)h) << 16;
  return c.f;
}

__device__ __forceinline__ f32x4 mfma16(short8 a, short8 b, f32x4 c) {
  return __builtin_amdgcn_mfma_f32_16x16x32_bf16(a, b, c, 0, 0, 0);
}

// ---------------- kernel 1: fp32 -> hi/lo bf16 split ----------------
__global__ __launch_bounds__(256) void k_convert(
    const float* __restrict__ x1, const float* __restrict__ x2, const float* __restrict__ x3,
    const float* __restrict__ wq, const float* __restrict__ wk, const float* __restrict__ wv,
    u16* __restrict__ wsu) {
  int b = blockIdx.x;
  const float* src; u16 *dh, *dl; int bl;
  if (b < 1024)      { src = x1; dh = wsu + XH0; dl = wsu + XL0; bl = b; }
  else if (b < 2048) { src = x2; dh = wsu + XH1; dl = wsu + XL1; bl = b - 1024; }
  else if (b < 3072) { src = x3; dh = wsu + XH2; dl = wsu + XL2; bl = b - 2048; }
  else if (b < 3104) { src = wq; dh = wsu + WQH; dl = wsu + WQL; bl = b - 3072; }
  else if (b < 3136) { src = wk; dh = wsu + WKH; dl = wsu + WKL; bl = b - 3104; }
  else               { src = wv; dh = wsu + WVH; dl = wsu + WVL; bl = b - 3136; }
  int i = (bl * 256 + threadIdx.x) * 8;
  f32x4 a = *(const f32x4*)(src + i);
  f32x4 c = *(const f32x4*)(src + i + 4);
  short8 rh, rl;
  float v[8] = {a[0], a[1], a[2], a[3], c[0], c[1], c[2], c[3]};
#pragma unroll
  for (int j = 0; j < 8; j++) {
    u16 h = f2bf(v[j]);
    rh[j] = (short)h;
    rl[j] = (short)f2bf(v[j] - bf2f(h));
  }
  *(short8*)(dh + i) = rh;
  *(short8*)(dl + i) = rl;
}

// ---------------- kernel 2: QKV projection, LDS-free direct-fragment GEMM ----------------
// NT gemm: out[m][nn] = sum_k A[m][k]*B[nn][k] + bias, 3-term hi/lo.
// All MFMA fragments are contiguous 16B global loads (L1/L2-hit); no barriers, no LDS.
// Block = 4 waves = 2m x 2n -> 64 rows x 32 cols. Grid 3 x 1024.
__global__ __launch_bounds__(256) void k_qkv(
    u16* __restrict__ wsu,
    const float* __restrict__ bq, const float* __restrict__ bk, const float* __restrict__ bv) {
  int bx = blockIdx.x;
  int mid = bx >> 10;
  int t = bx & 1023;
  const u16 *Ah, *Al, *Bh, *Bl; u16 *O; const float* bias;
  int rb, cb, ldO, biasRow;
  if (mid == 0) {
    Ah = wsu + XH0; Al = wsu + XL0; Bh = wsu + WQH; Bl = wsu + WQL;
    O = wsu + QH; bias = bq; biasRow = 0; ldO = 256;
    rb = t >> 3; cb = t & 7;
  } else if (mid == 1) {
    Ah = wsu + XH1; Al = wsu + XL1; Bh = wsu + WKH; Bl = wsu + WKL;
    O = wsu + KH; bias = bk; biasRow = 0; ldO = 256;
    rb = t >> 3; cb = t & 7;
  } else {
    Ah = wsu + WVH; Al = wsu + WVL; Bh = wsu + XH2; Bl = wsu + XL2;
    O = wsu + VTB; bias = bv; biasRow = 1; ldO = 8192;
    rb = t >> 8; cb = t & 255;
  }
  int lane = threadIdx.x & 63, wave = threadIdx.x >> 6;
  int n = lane & 15, quad = lane >> 4;
  int wm = wave >> 1, wn = wave & 1;
  int row0 = rb * 64 + wm * 32;
  int col0 = cb * 32 + wn * 16;

  const u16* pA0h = Ah + (size_t)(row0 + n) * 256 + quad * 8;
  const u16* pA0l = Al + (size_t)(row0 + n) * 256 + quad * 8;
  const u16* pA1h = pA0h + 16 * 256;
  const u16* pA1l = pA0l + 16 * 256;
  const u16* pBh  = Bh + (size_t)(col0 + n) * 256 + quad * 8;
  const u16* pBl  = Bl + (size_t)(col0 + n) * 256 + quad * 8;

  f32x4 acc0 = {0.f,0.f,0.f,0.f}, acc1 = {0.f,0.f,0.f,0.f};
#pragma unroll
  for (int kk = 0; kk < 8; kk++) {
    short8 a0h = *(const short8*)(pA0h + kk * 32);
    short8 a1h = *(const short8*)(pA1h + kk * 32);
    short8 a0l = *(const short8*)(pA0l + kk * 32);
    short8 a1l = *(const short8*)(pA1l + kk * 32);
    short8 bh  = *(const short8*)(pBh + kk * 32);
    short8 bl  = *(const short8*)(pBl + kk * 32);
    acc0 = mfma16(a0h, bh, acc0);
    acc1 = mfma16(a1h, bh, acc1);
    acc0 = mfma16(a0h, bl, acc0);
    acc1 = mfma16(a1h, bl, acc1);
    acc0 = mfma16(a0l, bh, acc0);
    acc1 = mfma16(a1l, bh, acc1);
  }
  int colg = col0 + n;
  float bcol = biasRow ? 0.0f : bias[colg];
#pragma unroll
  for (int mt = 0; mt < 2; mt++) {
    f32x4 acc = mt ? acc1 : acc0;
#pragma unroll
    for (int r = 0; r < 4; r++) {
      int rowg = row0 + mt * 16 + quad * 4 + r;
      float bb = biasRow ? bias[rowg] : bcol;
      O[(size_t)rowg * ldO + colg] = f2bf(acc[r] + bb);
    }
  }
}

// ---------------- kernel 3: flash attention v4 ----------------
// grid: 512 = 64 q-blocks x 8 key-splits; 4 waves x 32 q-rows. Double-buffered K/V
// staged via global->VGPR->ds_write into PADDED LDS (inner loop = base + immediate
// addressing, bank-conflict-free). Fixed-base softmax, one barrier/iter.
#define KSTR 260                 // K row stride (u16): 520 B == 2 mod 32 dwords
#define VSTR 36                  // V row stride (u16): 72 B == 18 mod 32 dwords
#define KBUF (32 * KSTR)         // 8320 u16 per K buffer
#define VBUF (256 * VSTR)        // 9216 u16 per V buffer
__global__ __launch_bounds__(256, 2) void k_flash(
    const u16* __restrict__ wsu, u16* __restrict__ opart, float* __restrict__ wsf) {
  __shared__ u16 sK[2 * KBUF];       // 2 x 16.25 KB
  __shared__ u16 sV[2 * VBUF];       // 2 x 18 KB
  __shared__ u16 sP[4 * 32 * 40];    // 10 KB: per-wave 32x32 P, stride 40

  int qb = blockIdx.x >> 3, sp = blockIdx.x & 7;   // split -> XCD pinning
  int tid = threadIdx.x, lane = tid & 63, wave = tid >> 6;
  int n = lane & 15, quad = lane >> 4;
  const u16* Qp = wsu + QH;
  const u16* Kp = wsu + KH;
  const u16* Vp = wsu + VTB;

  // Q fragments (A-layout) for 2 m-tiles: 64 VGPR
  short8 qf[2][8];
  int rowQ0 = qb * 128 + wave * 32 + n;
#pragma unroll
  for (int mt = 0; mt < 2; mt++)
#pragma unroll
    for (int kk = 0; kk < 8; kk++)
      qf[mt][kk] = *(const short8*)(Qp + (size_t)(rowQ0 + mt * 16) * 256 + kk * 32 + quad * 8);

  // staging lane geometry
  int kr = wave * 8 + (lane >> 3);                  // K row in tile (0..31)
  int ku = lane & 7;                                // K 16B-unit; pass i adds 8
  const u16* gK = Kp + (size_t)(sp * 1024 + kr) * 256 + ku * 8;   // += 8192/iter
  u16* lK = &sK[kr * KSTR + ku * 8];                // pass i: +64 elems; buf1: +KBUF

  int vd = wave * 64 + (lane >> 2);                 // V row (d); pass i adds 16
  int vu = lane & 3;
  const u16* gV = Vp + (size_t)vd * 8192 + sp * 1024 + vu * 8;    // += 32/iter
  u16* lV = &sV[vd * VSTR + vu * 8];                // pass i: +16*VSTR; buf1: +VBUF

  // preload tile 0 into buffer 0
  {
    short8 tk[4], tv[4];
#pragma unroll
    for (int i = 0; i < 4; i++) tk[i] = *(const short8*)(gK + i * 64);
#pragma unroll
    for (int i = 0; i < 4; i++) tv[i] = *(const short8*)(gV + (size_t)i * 16 * 8192);
    gK += 32 * 256; gV += 32;
#pragma unroll
    for (int i = 0; i < 4; i++) *(short8*)(lK + i * 64) = tk[i];
#pragma unroll
    for (int i = 0; i < 4; i++) *(short8*)(lV + i * 16 * VSTR) = tv[i];
  }

  f32x4 o[2][16];
#pragma unroll
  for (int mt = 0; mt < 2; mt++)
#pragma unroll
    for (int nt = 0; nt < 16; nt++) { o[mt][nt][0]=0.f; o[mt][nt][1]=0.f; o[mt][nt][2]=0.f; o[mt][nt][3]=0.f; }
  float negm0L[8], lcur[8];
#pragma unroll
  for (int j = 0; j < 8; j++) { negm0L[j] = 0.f; lcur[j] = 0.f; }

  // loop-invariant LDS bases (all inner LDS ops = base + compile-time immediate)
  const u16* rK = &sK[n * KSTR + quad * 8];   // b1: +16*KSTR; buf1: +KBUF
  const u16* rV = &sV[n * VSTR + quad * 8];   // nt: +nt*16*VSTR; buf1: +VBUF
  u16* myP = &sP[wave * 1280];
  u16* wP  = myP + quad * 160 + n;            // writes: +r*40 (+16 for n-tile 1)
  const u16* rP = &myP[n * 40 + quad * 8];    // pa1: +640

  // kRd/vRd: read-buffer offsets; kWr/vWr: write-buffer offsets (compile-time at call sites)
  auto body = [&](int kRd, int vRd, int kWr, int vWr, bool first) {
    __syncthreads();   // staged tile ready; all waves done with write-target buffer

    // S = Q K^T on read buffer: 32 MFMA, immediate-offset ds_reads
    f32x4 s00={0.f,0.f,0.f,0.f}, s01={0.f,0.f,0.f,0.f};
    f32x4 s10={0.f,0.f,0.f,0.f}, s11={0.f,0.f,0.f,0.f};
#pragma unroll
    for (int kk = 0; kk < 8; kk++) {
      short8 b0 = *(const short8*)(rK + kRd + kk * 32);
      short8 b1 = *(const short8*)(rK + kRd + 16 * KSTR + kk * 32);
      s00 = mfma16(qf[0][kk], b0, s00);
      s01 = mfma16(qf[0][kk], b1, s01);
      s10 = mfma16(qf[1][kk], b0, s10);
      s11 = mfma16(qf[1][kk], b1, s11);
    }

    // issue next-tile global loads (consumed by ds_write at end of body)
    short8 tk[4], tv[4];
#pragma unroll
    for (int i = 0; i < 4; i++) tk[i] = *(const short8*)(gK + i * 64);
#pragma unroll
    for (int i = 0; i < 4; i++) tv[i] = *(const short8*)(gV + (size_t)i * 16 * 8192);
    gK += 32 * 256; gV += 32;

    // fixed softmax base from first tile
    if (first) {
#pragma unroll
      for (int mt = 0; mt < 2; mt++)
#pragma unroll
        for (int r = 0; r < 4; r++) {
          float v = mt ? fmaxf(s10[r], s11[r]) : fmaxf(s00[r], s01[r]);
          v = fmaxf(v, __shfl_xor(v, 1));
          v = fmaxf(v, __shfl_xor(v, 2));
          v = fmaxf(v, __shfl_xor(v, 4));
          v = fmaxf(v, __shfl_xor(v, 8));
          negm0L[mt * 4 + r] = -v * LOG2E;
        }
    }

    // p = exp2(s*log2e + negm0), accumulate l, pack P to LDS (C->A transform)
#pragma unroll
    for (int mt = 0; mt < 2; mt++)
#pragma unroll
      for (int r = 0; r < 4; r++) {
        int j = mt * 4 + r;
        float sv0 = mt ? s10[r] : s00[r];
        float sv1 = mt ? s11[r] : s01[r];
        float x0 = fminf(fmaf(sv0, LOG2E, negm0L[j]), 110.f);
        float x1 = fminf(fmaf(sv1, LOG2E, negm0L[j]), 110.f);
        float p0 = exp2f(x0);
        float p1 = exp2f(x1);
        lcur[j] += p0 + p1;
        wP[(mt * 16) * 40 + r * 40]      = f2bf_hu(p0);
        wP[(mt * 16) * 40 + r * 40 + 16] = f2bf_hu(p1);
      }

    // PV: O[32 x 256] += P[32 x 32] @ V[32 x 256]
    short8 pa0 = *(const short8*)(rP);
    short8 pa1 = *(const short8*)(rP + 640);
#pragma unroll
    for (int nt = 0; nt < 16; nt++) {
      short8 vb = *(const short8*)(rV + vRd + nt * 16 * VSTR);
      o[0][nt] = mfma16(pa0, vb, o[0][nt]);
      o[1][nt] = mfma16(pa1, vb, o[1][nt]);
    }

    // write staged tile into the other buffer
#pragma unroll
    for (int i = 0; i < 4; i++) *(short8*)(lK + kWr + i * 64) = tk[i];
#pragma unroll
    for (int i = 0; i < 4; i++) *(short8*)(lV + vWr + i * 16 * VSTR) = tv[i];
  };

  // 32 iterations, unrolled x2 with hardcoded buffer offsets
#pragma unroll 1
  for (int ii = 0; ii < 16; ii++) {
    body(0, 0, KBUF, VBUF, ii == 0);
    body(KBUF, VBUF, 0, 0, false);
  }

  // reduce l across the 16 lanes sharing rows
#pragma unroll
  for (int j = 0; j < 8; j++) {
    float v = lcur[j];
    v += __shfl_xor(v, 1); v += __shfl_xor(v, 2);
    v += __shfl_xor(v, 4); v += __shfl_xor(v, 8);
    lcur[j] = v;
  }

  // store bf16 unnormalized partials + stats
  u16* op = opart + (size_t)sp * (NT * DH);
  int rowb = qb * 128 + wave * 32;
#pragma unroll
  for (int mt = 0; mt < 2; mt++)
#pragma unroll
    for (int nt = 0; nt < 16; nt++)
#pragma unroll
      for (int r = 0; r < 4; r++) {
        int row = rowb + mt * 16 + quad * 4 + r;
        op[(size_t)row * 256 + nt * 16 + n] = f2bf(o[mt][nt][r]);
      }
  if (n == 0) {
#pragma unroll
    for (int j = 0; j < 8; j++) {
      int row = rowb + (j >> 2) * 16 + quad * 4 + (j & 3);
      wsf[MPART_F + sp * NT + row] = negm0L[j] * -0.6931471805599453f;
      wsf[LPART_F + sp * NT + row] = lcur[j];
    }
  }
}

// ---------------- kernel 4: combine 8 splits ----------------
__global__ __launch_bounds__(256) void k_combine(
    const u16* __restrict__ opart, const float* __restrict__ wsf, float* __restrict__ out) {
  int gid = blockIdx.x * 256 + threadIdx.x;
  int row = gid >> 6, cg = gid & 63;
  float m[8], l[8];
#pragma unroll
  for (int s = 0; s < 8; s++) {
    m[s] = wsf[MPART_F + s * NT + row];
    l[s] = wsf[LPART_F + s * NT + row];
  }
  float ms = m[0];
#pragma unroll
  for (int s = 1; s < 8; s++) ms = fmaxf(ms, m[s]);
  float denom = 0.f;
  float acc[4] = {0.f, 0.f, 0.f, 0.f};
#pragma unroll
  for (int s = 0; s < 8; s++) {
    float w = exp2f((m[s] - ms) * LOG2E);
    denom += w * l[s];
    const u16* pp = opart + ((size_t)s * NT + row) * 256 + cg * 4;
    uint2 v = *(const uint2*)pp;
    acc[0] += w * bf2f((u16)(v.x & 0xffff));
    acc[1] += w * bf2f((u16)(v.x >> 16));
    acc[2] += w * bf2f((u16)(v.y & 0xffff));
    acc[3] += w * bf2f((u16)(v.y >> 16));
  }
  float inv = 1.0f / denom;
  f32x4 r = {acc[0] * inv, acc[1] * inv, acc[2] * inv, acc[3] * inv};
  *(f32x4*)(out + (size_t)row * 256 + cg * 4) = r;
}

extern "C" void kernel_launch(void* const* d_in, const int* in_sizes, int n_in,
                              void* d_out, int out_size, void* d_ws, size_t ws_size,
                              hipStream_t stream) {
  const float* x1 = (const float*)d_in[0];
  const float* x2 = (const float*)d_in[1];
  const float* x3 = (const float*)d_in[2];
  const float* Wq = (const float*)d_in[3];
  const float* bq = (const float*)d_in[4];
  const float* Wk = (const float*)d_in[5];
  const float* bk = (const float*)d_in[6];
  const float* Wv = (const float*)d_in[7];
  const float* bv = (const float*)d_in[8];
  u16* wsu = (u16*)d_ws;
  float* wsf = (float*)d_ws;
  float* out = (float*)d_out;

  k_convert<<<dim3(3168), dim3(256), 0, stream>>>(x1, x2, x3, Wq, Wk, Wv, wsu);
  k_qkv<<<dim3(3072), dim3(256), 0, stream>>>(wsu, bq, bk, bv);
  k_flash<<<dim3(512), dim3(256), 0, stream>>>(wsu, wsu + OPARTB, wsf);
  k_combine<<<dim3(2048), dim3(256), 0, stream>>>(wsu + OPARTB, wsf, out);
}

// Round 7
// 246.432 us; speedup vs baseline: 1.9345x; 1.9345x over previous
//
#include <hip/hip_runtime.h>
#include <stdint.h>

typedef unsigned short u16;
typedef __attribute__((ext_vector_type(8))) short short8;   // 8 bf16 = 4 VGPRs (MFMA A/B frag)
typedef __attribute__((ext_vector_type(4))) float f32x4;    // MFMA C/D frag

#define LOG2E 1.4426950408889634f
#define NT 8192
#define DH 256

// ---- workspace layout (u16 element offsets) ----
// persistent across flash:
#define QH     0
#define KH     2097152
#define VTB    4194304          // V transposed: [256][8192]
#define OPARTB 6291456          // 8 x [8192][256] bf16 unnormalized partial O (32 MB)
// temps (dead after k_qkv; deliberately overlap OPARTB region):
#define XH0 6291456
#define XL0 8388608
#define XH1 10485760
#define XL1 12582912
#define XH2 14680064
#define XL2 16777216
#define WQH 18874368
#define WQL 18939904
#define WKH 19005440
#define WKL 19070976
#define WVH 19136512
#define WVL 19202048
// fp32 region (float element offsets), after OPARTB (byte 46,137,344):
#define MPART_F 11534336        // 8 x [8192] per-split softmax base m0
#define LPART_F 11599872        // 8 x [8192] per-split denom

__device__ __forceinline__ u16 f2bf(float f) {
  union { float f; uint32_t u; } c; c.f = f;
  uint32_t u = c.u;
  return (u16)((u + 0x7fffu + ((u >> 16) & 1)) >> 16);   // RNE
}
__device__ __forceinline__ u16 f2bf_hu(float f) {        // round-half-up: 2 VALU ops
  union { float f; uint32_t u; } c; c.f = f;
  return (u16)((c.u + 0x8000u) >> 16);
}
__device__ __forceinline__ float bf2f(u16 h) {
  union { uint32_t u; float f; } c; c.u = ((uint32_t)h) << 16;
  return c.f;
}

// XOR swizzle for LDS rows of 32 16B-units (512B rows)
__device__ __forceinline__ int swz32(int u, int row) {
  return (u & 24) | ((u & 7) ^ (row & 7));
}

__device__ __forceinline__ f32x4 mfma16(short8 a, short8 b, f32x4 c) {
  return __builtin_amdgcn_mfma_f32_16x16x32_bf16(a, b, c, 0, 0, 0);
}

// async global->LDS, 16B per lane; LDS dest is wave-uniform base + lane*16
__device__ __forceinline__ void gl_lds16(const u16* g, u16* l) {
  __builtin_amdgcn_global_load_lds(
      (const __attribute__((address_space(1))) uint32_t*)g,
      (__attribute__((address_space(3))) uint32_t*)l, 16, 0, 0);
}

// ---------------- kernel 1: fp32 -> hi/lo bf16 split ----------------
__global__ __launch_bounds__(256) void k_convert(
    const float* __restrict__ x1, const float* __restrict__ x2, const float* __restrict__ x3,
    const float* __restrict__ wq, const float* __restrict__ wk, const float* __restrict__ wv,
    u16* __restrict__ wsu) {
  int b = blockIdx.x;
  const float* src; u16 *dh, *dl; int bl;
  if (b < 1024)      { src = x1; dh = wsu + XH0; dl = wsu + XL0; bl = b; }
  else if (b < 2048) { src = x2; dh = wsu + XH1; dl = wsu + XL1; bl = b - 1024; }
  else if (b < 3072) { src = x3; dh = wsu + XH2; dl = wsu + XL2; bl = b - 2048; }
  else if (b < 3104) { src = wq; dh = wsu + WQH; dl = wsu + WQL; bl = b - 3072; }
  else if (b < 3136) { src = wk; dh = wsu + WKH; dl = wsu + WKL; bl = b - 3104; }
  else               { src = wv; dh = wsu + WVH; dl = wsu + WVL; bl = b - 3136; }
  int i = (bl * 256 + threadIdx.x) * 8;
  f32x4 a = *(const f32x4*)(src + i);
  f32x4 c = *(const f32x4*)(src + i + 4);
  short8 rh, rl;
  float v[8] = {a[0], a[1], a[2], a[3], c[0], c[1], c[2], c[3]};
#pragma unroll
  for (int j = 0; j < 8; j++) {
    u16 h = f2bf(v[j]);
    rh[j] = (short)h;
    rl[j] = (short)f2bf(v[j] - bf2f(h));
  }
  *(short8*)(dh + i) = rh;
  *(short8*)(dl + i) = rl;
}

// ---------------- kernel 2: QKV projection (NT gemm, 3-term hi/lo bf16 MFMA) ----------------
// (R4 LDS-staged version — measured ~11 us faster than LDS-free direct-fragment)
__global__ __launch_bounds__(256) void k_qkv(
    u16* __restrict__ wsu,
    const float* __restrict__ bq, const float* __restrict__ bk, const float* __restrict__ bv) {
  __shared__ u16 sAh[64 * 256];
  __shared__ u16 sAl[64 * 256];
  __shared__ u16 sBh[32 * 256];
  __shared__ u16 sBl[32 * 256];
  int bx = blockIdx.x;
  int mid = bx >> 10;
  int t = bx & 1023;
  const u16 *Ah, *Al, *Bh, *Bl; u16 *Ohi; const float* bias;
  int rb, cb, ldO, biasRow;
  if (mid == 0) {
    Ah = wsu + XH0; Al = wsu + XL0; Bh = wsu + WQH; Bl = wsu + WQL;
    Ohi = wsu + QH; bias = bq; biasRow = 0; ldO = 256;
    rb = t >> 3; cb = t & 7;
  } else if (mid == 1) {
    Ah = wsu + XH1; Al = wsu + XL1; Bh = wsu + WKH; Bl = wsu + WKL;
    Ohi = wsu + KH; bias = bk; biasRow = 0; ldO = 256;
    rb = t >> 3; cb = t & 7;
  } else {
    Ah = wsu + WVH; Al = wsu + WVL; Bh = wsu + XH2; Bl = wsu + XL2;
    Ohi = wsu + VTB; bias = bv; biasRow = 1; ldO = 8192;
    rb = t >> 8; cb = t & 255;
  }

  int tid = threadIdx.x;
#pragma unroll
  for (int i = 0; i < 8; i++) {
    int L = i * 256 + tid;
    int row = L >> 5, u = L & 31;
    short8 vh = *(const short8*)(Ah + (rb * 64 + row) * 256 + u * 8);
    short8 vl = *(const short8*)(Al + (rb * 64 + row) * 256 + u * 8);
    *(short8*)(&sAh[row * 256 + swz32(u, row) * 8]) = vh;
    *(short8*)(&sAl[row * 256 + swz32(u, row) * 8]) = vl;
  }
#pragma unroll
  for (int i = 0; i < 4; i++) {
    int L = i * 256 + tid;
    int row = L >> 5, u = L & 31;
    short8 vh = *(const short8*)(Bh + (cb * 32 + row) * 256 + u * 8);
    short8 vl = *(const short8*)(Bl + (cb * 32 + row) * 256 + u * 8);
    *(short8*)(&sBh[row * 256 + swz32(u, row) * 8]) = vh;
    *(short8*)(&sBl[row * 256 + swz32(u, row) * 8]) = vl;
  }
  __syncthreads();

  int lane = tid & 63, wave = tid >> 6;
  int n = lane & 15, quad = lane >> 4;
  int wm = wave >> 1, wn = wave & 1;
  f32x4 acc0 = {0.f,0.f,0.f,0.f}, acc1 = {0.f,0.f,0.f,0.f};
#pragma unroll
  for (int kk = 0; kk < 8; kk++) {
    int ra = wm * 32 + n;
    int sa0 = ra * 256 + swz32(kk * 4 + quad, ra) * 8;
    int sa1 = (ra + 16) * 256 + swz32(kk * 4 + quad, ra + 16) * 8;
    short8 a0h = *(const short8*)(&sAh[sa0]);
    short8 a1h = *(const short8*)(&sAh[sa1]);
    short8 a0l = *(const short8*)(&sAl[sa0]);
    short8 a1l = *(const short8*)(&sAl[sa1]);
    int rbB = wn * 16 + n;
    int sb = rbB * 256 + swz32(kk * 4 + quad, rbB) * 8;
    short8 bh = *(const short8*)(&sBh[sb]);
    short8 bl = *(const short8*)(&sBl[sb]);
    acc0 = mfma16(a0h, bh, acc0);
    acc1 = mfma16(a1h, bh, acc1);
    acc0 = mfma16(a0h, bl, acc0);
    acc1 = mfma16(a1h, bl, acc1);
    acc0 = mfma16(a0l, bh, acc0);
    acc1 = mfma16(a1l, bh, acc1);
  }
  int colg = cb * 32 + wn * 16 + n;
  float bcol = biasRow ? 0.0f : bias[colg];
#pragma unroll
  for (int mt = 0; mt < 2; mt++) {
    f32x4 acc = mt ? acc1 : acc0;
#pragma unroll
    for (int r = 0; r < 4; r++) {
      int rowg = rb * 64 + wm * 32 + mt * 16 + quad * 4 + r;
      float bb = biasRow ? bias[rowg] : bcol;
      Ohi[rowg * ldO + colg] = f2bf(acc[r] + bb);
    }
  }
}

// ---------------- kernel 3: flash attention v5 (R4 structure + VALU cuts) ----------------
// grid: 512 = 64 q-blocks x 8 key-splits; 4 waves x 32 q-rows. Double-buffered K/V via
// gl_lds16 (no VGPR staging -> no spills), swizzled LDS, 1 barrier/iter, fixed-base softmax.
// New vs R4: pointer-increment staging addrs, unrolled x2 compile-time buffers, no clamp.
__global__ __launch_bounds__(256, 2) void k_flash(
    const u16* __restrict__ wsu, u16* __restrict__ opart, float* __restrict__ wsf) {
  __shared__ u16 sK[2][32 * 256];    // 2 x 16 KB
  __shared__ u16 sV[2][256 * 32];    // 2 x 16 KB
  __shared__ u16 sP[4 * 32 * 40];    // 10 KB: per-wave 32x32 P, stride 40

  int qb = blockIdx.x >> 3, sp = blockIdx.x & 7;   // split -> XCD pinning
  int tid = threadIdx.x, lane = tid & 63, wave = tid >> 6;
  int n = lane & 15, quad = lane >> 4;
  const u16* Qp = wsu + QH;
  const u16* Kp = wsu + KH;
  const u16* Vp = wsu + VTB;

  // Q fragments (A-layout) for 2 m-tiles: 64 VGPR
  short8 qf[2][8];
  int rowQ0 = qb * 128 + wave * 32 + n;
#pragma unroll
  for (int mt = 0; mt < 2; mt++)
#pragma unroll
    for (int kk = 0; kk < 8; kk++)
      qf[mt][kk] = *(const short8*)(Qp + (size_t)(rowQ0 + mt * 16) * 256 + kk * 32 + quad * 8);

  // staging lane geometry (computed once; inverse swizzle folded into base pointers)
  int krow_base = wave * 2 + (lane >> 5);                  // K row = i*8 + krow_base
  int kgu = (lane & 24) | ((lane & 7) ^ (krow_base & 7));  // inverse-swizzled source unit
  int vd_base = wave * 16 + (lane >> 2);                   // V d = i*64 + vd_base
  int vgu = (lane & 3) ^ ((lane >> 3) & 3);

  int key00 = sp * 1024;
  const u16* gK[4];
  const u16* gV[4];
#pragma unroll
  for (int i = 0; i < 4; i++) {
    gK[i] = Kp + (size_t)(key00 + i * 8 + krow_base) * 256 + kgu * 8;   // += 8192/iter
    gV[i] = Vp + (size_t)(i * 64 + vd_base) * 8192 + key00 + vgu * 8;   // += 32/iter
  }

  // preload tile 0 into buffer 0
#pragma unroll
  for (int i = 0; i < 4; i++) {
    gl_lds16(gK[i], &sK[0][i * 2048 + wave * 512]);
    gl_lds16(gV[i], &sV[0][i * 2048 + wave * 512]);
    gK[i] += 32 * 256;
    gV[i] += 32;
  }

  f32x4 o[2][16];
#pragma unroll
  for (int mt = 0; mt < 2; mt++)
#pragma unroll
    for (int nt = 0; nt < 16; nt++) { o[mt][nt][0]=0.f; o[mt][nt][1]=0.f; o[mt][nt][2]=0.f; o[mt][nt][3]=0.f; }
  float negm0L[8], lcur[8];
#pragma unroll
  for (int j = 0; j < 8; j++) { negm0L[j] = 0.f; lcur[j] = 0.f; }

  u16* myP = &sP[wave * 1280];

  // rbuf = read buffer, wbuf = write (prefetch) buffer — compile-time at both call sites
  auto body = [&](int rbuf, int wbuf, int it, bool first) {
    __syncthreads();   // drains vmcnt: buf[rbuf] DMA complete; all waves done with buf[wbuf]

    // prefetch next tile (async DMA; pointer-increment addressing only)
    if (it < 31) {
#pragma unroll
      for (int i = 0; i < 4; i++) {
        gl_lds16(gK[i], &sK[wbuf][i * 2048 + wave * 512]);
        gl_lds16(gV[i], &sV[wbuf][i * 2048 + wave * 512]);
        gK[i] += 32 * 256;
        gV[i] += 32;
      }
    }

    // S = Q K^T: 2 m-tiles x 2 n-tiles x 8 ksteps = 32 MFMA
    f32x4 s00={0.f,0.f,0.f,0.f}, s01={0.f,0.f,0.f,0.f};
    f32x4 s10={0.f,0.f,0.f,0.f}, s11={0.f,0.f,0.f,0.f};
#pragma unroll
    for (int kk = 0; kk < 8; kk++) {
      int su = swz32(kk * 4 + quad, n) * 8;       // loop-invariant across it; hoisted
      short8 b0 = *(const short8*)(&sK[rbuf][n * 256 + su]);
      short8 b1 = *(const short8*)(&sK[rbuf][(n + 16) * 256 + su]);
      s00 = mfma16(qf[0][kk], b0, s00);
      s01 = mfma16(qf[0][kk], b1, s01);
      s10 = mfma16(qf[1][kk], b0, s10);
      s11 = mfma16(qf[1][kk], b1, s11);
    }

    // fixed softmax base from first tile
    if (first) {
#pragma unroll
      for (int mt = 0; mt < 2; mt++)
#pragma unroll
        for (int r = 0; r < 4; r++) {
          float v = mt ? fmaxf(s10[r], s11[r]) : fmaxf(s00[r], s01[r]);
          v = fmaxf(v, __shfl_xor(v, 1));
          v = fmaxf(v, __shfl_xor(v, 2));
          v = fmaxf(v, __shfl_xor(v, 4));
          v = fmaxf(v, __shfl_xor(v, 8));
          negm0L[mt * 4 + r] = -v * LOG2E;
        }
    }

    // p = exp2(s*log2e + negm0) (unclamped: bounded logits), accumulate l, pack P to LDS
#pragma unroll
    for (int mt = 0; mt < 2; mt++)
#pragma unroll
      for (int r = 0; r < 4; r++) {
        int j = mt * 4 + r;
        float sv0 = mt ? s10[r] : s00[r];
        float sv1 = mt ? s11[r] : s01[r];
        float p0 = exp2f(fmaf(sv0, LOG2E, negm0L[j]));
        float p1 = exp2f(fmaf(sv1, LOG2E, negm0L[j]));
        lcur[j] += p0 + p1;
        int row = mt * 16 + quad * 4 + r;
        myP[row * 40 + n] = f2bf_hu(p0);
        myP[row * 40 + 16 + n] = f2bf_hu(p1);
      }

    // PV: O[32 x 256] += P[32 x 32] @ V[32 x 256]
    short8 pa0 = *(const short8*)(&myP[n * 40 + quad * 8]);
    short8 pa1 = *(const short8*)(&myP[(16 + n) * 40 + quad * 8]);
#pragma unroll
    for (int nt = 0; nt < 16; nt++) {
      int d = nt * 16 + n;
      short8 vb = *(const short8*)(&sV[rbuf][d * 32 + (quad ^ ((n >> 1) & 3)) * 8]);
      o[0][nt] = mfma16(pa0, vb, o[0][nt]);
      o[1][nt] = mfma16(pa1, vb, o[1][nt]);
    }
  };

#pragma unroll 1
  for (int ii = 0; ii < 16; ii++) {
    body(0, 1, 2 * ii, ii == 0);
    body(1, 0, 2 * ii + 1, false);
  }

  // reduce l across the 16 lanes sharing rows
#pragma unroll
  for (int j = 0; j < 8; j++) {
    float v = lcur[j];
    v += __shfl_xor(v, 1); v += __shfl_xor(v, 2);
    v += __shfl_xor(v, 4); v += __shfl_xor(v, 8);
    lcur[j] = v;
  }

  // store bf16 unnormalized partials + stats
  u16* op = opart + (size_t)sp * (NT * DH);
  int rowb = qb * 128 + wave * 32;
#pragma unroll
  for (int mt = 0; mt < 2; mt++)
#pragma unroll
    for (int nt = 0; nt < 16; nt++)
#pragma unroll
      for (int r = 0; r < 4; r++) {
        int row = rowb + mt * 16 + quad * 4 + r;
        op[(size_t)row * 256 + nt * 16 + n] = f2bf(o[mt][nt][r]);
      }
  if (n == 0) {
#pragma unroll
    for (int j = 0; j < 8; j++) {
      int row = rowb + (j >> 2) * 16 + quad * 4 + (j & 3);
      wsf[MPART_F + sp * NT + row] = negm0L[j] * -0.6931471805599453f;
      wsf[LPART_F + sp * NT + row] = lcur[j];
    }
  }
}

// ---------------- kernel 4: combine 8 splits ----------------
__global__ __launch_bounds__(256) void k_combine(
    const u16* __restrict__ opart, const float* __restrict__ wsf, float* __restrict__ out) {
  int gid = blockIdx.x * 256 + threadIdx.x;
  int row = gid >> 6, cg = gid & 63;
  float m[8], l[8];
#pragma unroll
  for (int s = 0; s < 8; s++) {
    m[s] = wsf[MPART_F + s * NT + row];
    l[s] = wsf[LPART_F + s * NT + row];
  }
  float ms = m[0];
#pragma unroll
  for (int s = 1; s < 8; s++) ms = fmaxf(ms, m[s]);
  float denom = 0.f;
  float acc[4] = {0.f, 0.f, 0.f, 0.f};
#pragma unroll
  for (int s = 0; s < 8; s++) {
    float w = exp2f((m[s] - ms) * LOG2E);
    denom += w * l[s];
    const u16* pp = opart + ((size_t)s * NT + row) * 256 + cg * 4;
    uint2 v = *(const uint2*)pp;
    acc[0] += w * bf2f((u16)(v.x & 0xffff));
    acc[1] += w * bf2f((u16)(v.x >> 16));
    acc[2] += w * bf2f((u16)(v.y & 0xffff));
    acc[3] += w * bf2f((u16)(v.y >> 16));
  }
  float inv = 1.0f / denom;
  f32x4 r = {acc[0] * inv, acc[1] * inv, acc[2] * inv, acc[3] * inv};
  *(f32x4*)(out + (size_t)row * 256 + cg * 4) = r;
}

extern "C" void kernel_launch(void* const* d_in, const int* in_sizes, int n_in,
                              void* d_out, int out_size, void* d_ws, size_t ws_size,
                              hipStream_t stream) {
  const float* x1 = (const float*)d_in[0];
  const float* x2 = (const float*)d_in[1];
  const float* x3 = (const float*)d_in[2];
  const float* Wq = (const float*)d_in[3];
  const float* bq = (const float*)d_in[4];
  const float* Wk = (const float*)d_in[5];
  const float* bk = (const float*)d_in[6];
  const float* Wv = (const float*)d_in[7];
  const float* bv = (const float*)d_in[8];
  u16* wsu = (u16*)d_ws;
  float* wsf = (float*)d_ws;
  float* out = (float*)d_out;

  k_convert<<<dim3(3168), dim3(256), 0, stream>>>(x1, x2, x3, Wq, Wk, Wv, wsu);
  k_qkv<<<dim3(3072), dim3(256), 0, stream>>>(wsu, bq, bk, bv);
  k_flash<<<dim3(512), dim3(256), 0, stream>>>(wsu, wsu + OPARTB, wsf);
  k_combine<<<dim3(2048), dim3(256), 0, stream>>>(wsu + OPARTB, wsf, out);
}

// Round 8
// 230.033 us; speedup vs baseline: 2.0724x; 1.0713x over previous
//
#include <hip/hip_runtime.h>
#include <stdint.h>

typedef unsigned short u16;
typedef __attribute__((ext_vector_type(8))) short short8;   // 8 bf16 = 4 VGPRs (MFMA A/B frag)
typedef __attribute__((ext_vector_type(4))) float f32x4;    // MFMA C/D frag

#define LOG2E 1.4426950408889634f
#define NT 8192
#define DH 256

// ---- workspace layout (u16 element offsets) ----
// persistent across flash:
#define QH     0
#define KH     2097152
#define VTB    4194304          // V transposed: [256][8192]
#define OPARTB 6291456          // 8 x [8192][256] bf16 unnormalized partial O (32 MB)
// temps (dead after k_qkv; deliberately overlap OPARTB region):
#define XH0 6291456
#define XL0 8388608
#define XH1 10485760
#define XL1 12582912
#define XH2 14680064
#define XL2 16777216
#define WQH 18874368
#define WQL 18939904
#define WKH 19005440
#define WKL 19070976
#define WVH 19136512
#define WVL 19202048
// fp32 region (float element offsets), after OPARTB (byte 46,137,344):
#define MPART_F 11534336        // 8 x [8192] per-split softmax base m0
#define LPART_F 11599872        // 8 x [8192] per-split denom

__device__ __forceinline__ u16 f2bf(float f) {
  union { float f; uint32_t u; } c; c.f = f;
  uint32_t u = c.u;
  return (u16)((u + 0x7fffu + ((u >> 16) & 1)) >> 16);   // RNE
}
__device__ __forceinline__ u16 f2bf_hu(float f) {        // round-half-up: 2 VALU ops
  union { float f; uint32_t u; } c; c.f = f;
  return (u16)((c.u + 0x8000u) >> 16);
}
__device__ __forceinline__ float bf2f(u16 h) {
  union { uint32_t u; float f; } c; c.u = ((uint32_t)h) << 16;
  return c.f;
}

// XOR swizzle for LDS rows of 32 16B-units (512B rows)
__device__ __forceinline__ int swz32(int u, int row) {
  return (u & 24) | ((u & 7) ^ (row & 7));
}

__device__ __forceinline__ f32x4 mfma16(short8 a, short8 b, f32x4 c) {
  return __builtin_amdgcn_mfma_f32_16x16x32_bf16(a, b, c, 0, 0, 0);
}

// async global->LDS, 16B per lane; LDS dest is wave-uniform base + lane*16
__device__ __forceinline__ void gl_lds16(const u16* g, u16* l) {
  __builtin_amdgcn_global_load_lds(
      (const __attribute__((address_space(1))) uint32_t*)g,
      (__attribute__((address_space(3))) uint32_t*)l, 16, 0, 0);
}

// ---------------- kernel 1: fp32 -> hi/lo bf16 split ----------------
__global__ __launch_bounds__(256) void k_convert(
    const float* __restrict__ x1, const float* __restrict__ x2, const float* __restrict__ x3,
    const float* __restrict__ wq, const float* __restrict__ wk, const float* __restrict__ wv,
    u16* __restrict__ wsu) {
  int b = blockIdx.x;
  const float* src; u16 *dh, *dl; int bl;
  if (b < 1024)      { src = x1; dh = wsu + XH0; dl = wsu + XL0; bl = b; }
  else if (b < 2048) { src = x2; dh = wsu + XH1; dl = wsu + XL1; bl = b - 1024; }
  else if (b < 3072) { src = x3; dh = wsu + XH2; dl = wsu + XL2; bl = b - 2048; }
  else if (b < 3104) { src = wq; dh = wsu + WQH; dl = wsu + WQL; bl = b - 3072; }
  else if (b < 3136) { src = wk; dh = wsu + WKH; dl = wsu + WKL; bl = b - 3104; }
  else               { src = wv; dh = wsu + WVH; dl = wsu + WVL; bl = b - 3136; }
  int i = (bl * 256 + threadIdx.x) * 8;
  f32x4 a = *(const f32x4*)(src + i);
  f32x4 c = *(const f32x4*)(src + i + 4);
  short8 rh, rl;
  float v[8] = {a[0], a[1], a[2], a[3], c[0], c[1], c[2], c[3]};
#pragma unroll
  for (int j = 0; j < 8; j++) {
    u16 h = f2bf(v[j]);
    rh[j] = (short)h;
    rl[j] = (short)f2bf(v[j] - bf2f(h));
  }
  *(short8*)(dh + i) = rh;
  *(short8*)(dl + i) = rl;
}

// ---------------- kernel 2: QKV projection v2 ----------------
// NT gemm, 3-term hi/lo. A-tile (64 rows hi+lo) staged in LDS (64 KB -> 2 blocks/CU);
// B fragments read DIRECTLY from global (contiguous 16B, loop-invariant addresses +
// immediate offsets, L1/L2-hot) — no B staging, half the barrier'd LDS footprint of R4.
__global__ __launch_bounds__(256) void k_qkv(
    u16* __restrict__ wsu,
    const float* __restrict__ bq, const float* __restrict__ bk, const float* __restrict__ bv) {
  __shared__ u16 sAh[64 * 256];   // 32 KB
  __shared__ u16 sAl[64 * 256];   // 32 KB
  int bx = blockIdx.x;
  int mid = bx >> 10;
  int t = bx & 1023;
  const u16 *Ah, *Al, *Bh, *Bl; u16 *Ohi; const float* bias;
  int rb, cb, ldO, biasRow;
  if (mid == 0) {
    Ah = wsu + XH0; Al = wsu + XL0; Bh = wsu + WQH; Bl = wsu + WQL;
    Ohi = wsu + QH; bias = bq; biasRow = 0; ldO = 256;
    rb = t >> 3; cb = t & 7;
  } else if (mid == 1) {
    Ah = wsu + XH1; Al = wsu + XL1; Bh = wsu + WKH; Bl = wsu + WKL;
    Ohi = wsu + KH; bias = bk; biasRow = 0; ldO = 256;
    rb = t >> 3; cb = t & 7;
  } else {
    Ah = wsu + WVH; Al = wsu + WVL; Bh = wsu + XH2; Bl = wsu + XL2;
    Ohi = wsu + VTB; bias = bv; biasRow = 1; ldO = 8192;
    rb = t >> 8; cb = t & 255;
  }

  int tid = threadIdx.x;
#pragma unroll
  for (int i = 0; i < 8; i++) {            // stage A hi/lo: 64 rows x 32 units each
    int L = i * 256 + tid;
    int row = L >> 5, u = L & 31;
    short8 vh = *(const short8*)(Ah + (rb * 64 + row) * 256 + u * 8);
    short8 vl = *(const short8*)(Al + (rb * 64 + row) * 256 + u * 8);
    *(short8*)(&sAh[row * 256 + swz32(u, row) * 8]) = vh;
    *(short8*)(&sAl[row * 256 + swz32(u, row) * 8]) = vl;
  }

  int lane = tid & 63, wave = tid >> 6;
  int n = lane & 15, quad = lane >> 4;
  int wm = wave >> 1, wn = wave & 1;
  int col0 = cb * 32 + wn * 16;
  const u16* pBh = Bh + (size_t)(col0 + n) * 256 + quad * 8;
  const u16* pBl = Bl + (size_t)(col0 + n) * 256 + quad * 8;

  __syncthreads();

  f32x4 acc0 = {0.f,0.f,0.f,0.f}, acc1 = {0.f,0.f,0.f,0.f};
#pragma unroll
  for (int kk = 0; kk < 8; kk++) {
    int ra = wm * 32 + n;
    int sa0 = ra * 256 + swz32(kk * 4 + quad, ra) * 8;
    int sa1 = (ra + 16) * 256 + swz32(kk * 4 + quad, ra + 16) * 8;
    short8 a0h = *(const short8*)(&sAh[sa0]);
    short8 a1h = *(const short8*)(&sAh[sa1]);
    short8 a0l = *(const short8*)(&sAl[sa0]);
    short8 a1l = *(const short8*)(&sAl[sa1]);
    short8 bh  = *(const short8*)(pBh + kk * 32);
    short8 bl  = *(const short8*)(pBl + kk * 32);
    acc0 = mfma16(a0h, bh, acc0);
    acc1 = mfma16(a1h, bh, acc1);
    acc0 = mfma16(a0h, bl, acc0);
    acc1 = mfma16(a1h, bl, acc1);
    acc0 = mfma16(a0l, bh, acc0);
    acc1 = mfma16(a1l, bh, acc1);
  }
  int colg = col0 + n;
  float bcol = biasRow ? 0.0f : bias[colg];
#pragma unroll
  for (int mt = 0; mt < 2; mt++) {
    f32x4 acc = mt ? acc1 : acc0;
#pragma unroll
    for (int r = 0; r < 4; r++) {
      int rowg = rb * 64 + wm * 32 + mt * 16 + quad * 4 + r;
      float bb = biasRow ? bias[rowg] : bcol;
      Ohi[(size_t)rowg * ldO + colg] = f2bf(acc[r] + bb);
    }
  }
}

// ---------------- kernel 3: flash attention (R4 structure, verbatim) ----------------
// grid: 512 = 64 q-blocks x 8 key-splits; 4 waves x 32 q-rows each.
// Double-buffered K/V via gl_lds16 (no VGPR staging), one barrier/iter,
// fixed-base softmax. Per-iter address recompute — adding persistent pointer
// state here caused spills twice (R6, R7); do not "optimize" this again.
__global__ __launch_bounds__(256, 2) void k_flash(
    const u16* __restrict__ wsu, u16* __restrict__ opart, float* __restrict__ wsf) {
  __shared__ u16 sK[2][32 * 256];    // 2 x 16 KB
  __shared__ u16 sV[2][256 * 32];    // 2 x 16 KB
  __shared__ u16 sP[4 * 32 * 40];    // 10 KB: per-wave 32x32 P, stride 40

  int qb = blockIdx.x >> 3, sp = blockIdx.x & 7;   // split -> XCD pinning
  int tid = threadIdx.x, lane = tid & 63, wave = tid >> 6;
  int n = lane & 15, quad = lane >> 4;
  const u16* Qp = wsu + QH;
  const u16* Kp = wsu + KH;
  const u16* Vp = wsu + VTB;

  // Q fragments (A-layout) for 2 m-tiles: 64 VGPR
  short8 qf[2][8];
  int rowQ0 = qb * 128 + wave * 32 + n;
#pragma unroll
  for (int mt = 0; mt < 2; mt++)
#pragma unroll
    for (int kk = 0; kk < 8; kk++)
      qf[mt][kk] = *(const short8*)(Qp + (size_t)(rowQ0 + mt * 16) * 256 + kk * 32 + quad * 8);

  // staging lane geometry
  int krow_base = wave * 2 + (lane >> 5);                  // K row = i*8 + krow_base
  int kgu = (lane & 24) | ((lane & 7) ^ (krow_base & 7));  // inverse-swizzled source unit
  int vd_base = wave * 16 + (lane >> 2);                   // V d = i*64 + vd_base
  int vgu = (lane & 3) ^ ((lane >> 3) & 3);

  int key00 = sp * 1024;

  // preload tile 0 into buffer 0
#pragma unroll
  for (int i = 0; i < 4; i++) {
    gl_lds16(Kp + (size_t)(key00 + i * 8 + krow_base) * 256 + kgu * 8,
             &sK[0][i * 2048 + wave * 512]);
    gl_lds16(Vp + (size_t)(i * 64 + vd_base) * 8192 + key00 + vgu * 8,
             &sV[0][i * 2048 + wave * 512]);
  }

  f32x4 o[2][16];
#pragma unroll
  for (int mt = 0; mt < 2; mt++)
#pragma unroll
    for (int nt = 0; nt < 16; nt++) { o[mt][nt][0]=0.f; o[mt][nt][1]=0.f; o[mt][nt][2]=0.f; o[mt][nt][3]=0.f; }
  float negm0L[8], lcur[8];
#pragma unroll
  for (int j = 0; j < 8; j++) { negm0L[j] = 0.f; lcur[j] = 0.f; }

  for (int it = 0; it < 32; it++) {
    __syncthreads();   // drains vmcnt: buf[cur] loads complete; all waves done with buf[cur^1]
    int cur = it & 1;
    if (it + 1 < 32) {
      int k1 = key00 + (it + 1) * 32;
#pragma unroll
      for (int i = 0; i < 4; i++) {
        gl_lds16(Kp + (size_t)(k1 + i * 8 + krow_base) * 256 + kgu * 8,
                 &sK[cur ^ 1][i * 2048 + wave * 512]);
        gl_lds16(Vp + (size_t)(i * 64 + vd_base) * 8192 + k1 + vgu * 8,
                 &sV[cur ^ 1][i * 2048 + wave * 512]);
      }
    }

    // S = Q K^T: 2 m-tiles x 2 n-tiles x 8 ksteps = 32 MFMA
    f32x4 s00={0.f,0.f,0.f,0.f}, s01={0.f,0.f,0.f,0.f};
    f32x4 s10={0.f,0.f,0.f,0.f}, s11={0.f,0.f,0.f,0.f};
#pragma unroll
    for (int kk = 0; kk < 8; kk++) {
      int su = swz32(kk * 4 + quad, n) * 8;       // n and n+16 share (row&7) -> same su
      short8 b0 = *(const short8*)(&sK[cur][n * 256 + su]);
      short8 b1 = *(const short8*)(&sK[cur][(n + 16) * 256 + su]);
      s00 = mfma16(qf[0][kk], b0, s00);
      s01 = mfma16(qf[0][kk], b1, s01);
      s10 = mfma16(qf[1][kk], b0, s10);
      s11 = mfma16(qf[1][kk], b1, s11);
    }

    // fixed softmax base from first tile (no online rescale; logits bounded)
    if (it == 0) {
#pragma unroll
      for (int mt = 0; mt < 2; mt++)
#pragma unroll
        for (int r = 0; r < 4; r++) {
          float v = mt ? fmaxf(s10[r], s11[r]) : fmaxf(s00[r], s01[r]);
          v = fmaxf(v, __shfl_xor(v, 1));
          v = fmaxf(v, __shfl_xor(v, 2));
          v = fmaxf(v, __shfl_xor(v, 4));
          v = fmaxf(v, __shfl_xor(v, 8));
          negm0L[mt * 4 + r] = -v * LOG2E;
        }
    }

    // p = exp2(s*log2e + negm0), clamped; accumulate l; pack to LDS (C->A transform)
    u16* myP = &sP[wave * 1280];
#pragma unroll
    for (int mt = 0; mt < 2; mt++)
#pragma unroll
      for (int r = 0; r < 4; r++) {
        int j = mt * 4 + r;
        float sv0 = mt ? s10[r] : s00[r];
        float sv1 = mt ? s11[r] : s01[r];
        float x0 = fminf(fmaf(sv0, LOG2E, negm0L[j]), 110.f);
        float x1 = fminf(fmaf(sv1, LOG2E, negm0L[j]), 110.f);
        float p0 = exp2f(x0);
        float p1 = exp2f(x1);
        lcur[j] += p0 + p1;
        int row = mt * 16 + quad * 4 + r;
        myP[row * 40 + n] = f2bf_hu(p0);
        myP[row * 40 + 16 + n] = f2bf_hu(p1);
      }

    // PV: O[32 x 256] += P[32 x 32] @ V[32 x 256]
    u16* myP2 = &sP[wave * 1280];
    short8 pa0 = *(const short8*)(&myP2[n * 40 + quad * 8]);
    short8 pa1 = *(const short8*)(&myP2[(16 + n) * 40 + quad * 8]);
#pragma unroll
    for (int nt = 0; nt < 16; nt++) {
      int d = nt * 16 + n;
      short8 vb = *(const short8*)(&sV[cur][d * 32 + (quad ^ ((n >> 1) & 3)) * 8]);
      o[0][nt] = mfma16(pa0, vb, o[0][nt]);
      o[1][nt] = mfma16(pa1, vb, o[1][nt]);
    }
  }

  // reduce l across the 16 lanes sharing rows
#pragma unroll
  for (int j = 0; j < 8; j++) {
    float v = lcur[j];
    v += __shfl_xor(v, 1); v += __shfl_xor(v, 2);
    v += __shfl_xor(v, 4); v += __shfl_xor(v, 8);
    lcur[j] = v;
  }

  // store bf16 unnormalized partials + stats
  u16* op = opart + (size_t)sp * (NT * DH);
  int rowb = qb * 128 + wave * 32;
#pragma unroll
  for (int mt = 0; mt < 2; mt++)
#pragma unroll
    for (int nt = 0; nt < 16; nt++)
#pragma unroll
      for (int r = 0; r < 4; r++) {
        int row = rowb + mt * 16 + quad * 4 + r;
        op[(size_t)row * 256 + nt * 16 + n] = f2bf(o[mt][nt][r]);
      }
  if (n == 0) {
#pragma unroll
    for (int j = 0; j < 8; j++) {
      int row = rowb + (j >> 2) * 16 + quad * 4 + (j & 3);
      wsf[MPART_F + sp * NT + row] = negm0L[j] * -0.6931471805599453f;
      wsf[LPART_F + sp * NT + row] = lcur[j];
    }
  }
}

// ---------------- kernel 4: combine 8 splits ----------------
__global__ __launch_bounds__(256) void k_combine(
    const u16* __restrict__ opart, const float* __restrict__ wsf, float* __restrict__ out) {
  int gid = blockIdx.x * 256 + threadIdx.x;
  int row = gid >> 6, cg = gid & 63;
  float m[8], l[8];
#pragma unroll
  for (int s = 0; s < 8; s++) {
    m[s] = wsf[MPART_F + s * NT + row];
    l[s] = wsf[LPART_F + s * NT + row];
  }
  float ms = m[0];
#pragma unroll
  for (int s = 1; s < 8; s++) ms = fmaxf(ms, m[s]);
  float denom = 0.f;
  float acc[4] = {0.f, 0.f, 0.f, 0.f};
#pragma unroll
  for (int s = 0; s < 8; s++) {
    float w = exp2f((m[s] - ms) * LOG2E);
    denom += w * l[s];
    const u16* pp = opart + ((size_t)s * NT + row) * 256 + cg * 4;
    uint2 v = *(const uint2*)pp;
    acc[0] += w * bf2f((u16)(v.x & 0xffff));
    acc[1] += w * bf2f((u16)(v.x >> 16));
    acc[2] += w * bf2f((u16)(v.y & 0xffff));
    acc[3] += w * bf2f((u16)(v.y >> 16));
  }
  float inv = 1.0f / denom;
  f32x4 r = {acc[0] * inv, acc[1] * inv, acc[2] * inv, acc[3] * inv};
  *(f32x4*)(out + (size_t)row * 256 + cg * 4) = r;
}

extern "C" void kernel_launch(void* const* d_in, const int* in_sizes, int n_in,
                              void* d_out, int out_size, void* d_ws, size_t ws_size,
                              hipStream_t stream) {
  const float* x1 = (const float*)d_in[0];
  const float* x2 = (const float*)d_in[1];
  const float* x3 = (const float*)d_in[2];
  const float* Wq = (const float*)d_in[3];
  const float* bq = (const float*)d_in[4];
  const float* Wk = (const float*)d_in[5];
  const float* bk = (const float*)d_in[6];
  const float* Wv = (const float*)d_in[7];
  const float* bv = (const float*)d_in[8];
  u16* wsu = (u16*)d_ws;
  float* wsf = (float*)d_ws;
  float* out = (float*)d_out;

  k_convert<<<dim3(3168), dim3(256), 0, stream>>>(x1, x2, x3, Wq, Wk, Wv, wsu);
  k_qkv<<<dim3(3072), dim3(256), 0, stream>>>(wsu, bq, bk, bv);
  k_flash<<<dim3(512), dim3(256), 0, stream>>>(wsu, wsu + OPARTB, wsf);
  k_combine<<<dim3(2048), dim3(256), 0, stream>>>(wsu + OPARTB, wsf, out);
}

// Round 9
// 223.776 us; speedup vs baseline: 2.1304x; 1.0280x over previous
//
#include <hip/hip_runtime.h>
#include <stdint.h>

typedef unsigned short u16;
typedef __attribute__((ext_vector_type(8))) short short8;   // 8 bf16 = 4 VGPRs (MFMA A/B frag)
typedef __attribute__((ext_vector_type(4))) float f32x4;    // MFMA C/D frag

#define LOG2E 1.4426950408889634f
#define NT 8192
#define DH 256

// ---- workspace layout (u16 element offsets) ----
// persistent across flash:
#define QH     0
#define KH     2097152
#define VTB    4194304          // V transposed: [256][8192]
#define OPARTB 6291456          // 8 x [8192][256] bf16 unnormalized partial O (32 MB)
// temps (dead after k_qkv; deliberately overlap OPARTB region):
#define XH0 6291456
#define XL0 8388608
#define XH1 10485760
#define XL1 12582912
#define XH2 14680064
#define XL2 16777216
#define WQH 18874368
#define WQL 18939904
#define WKH 19005440
#define WKL 19070976
#define WVH 19136512
#define WVL 19202048
// fp32 region (float element offsets), after OPARTB (byte 46,137,344):
#define MPART_F 11534336        // 8 x [8192] per-split softmax base m0
#define LPART_F 11599872        // 8 x [8192] per-split denom

__device__ __forceinline__ u16 f2bf(float f) {
  union { float f; uint32_t u; } c; c.f = f;
  uint32_t u = c.u;
  return (u16)((u + 0x7fffu + ((u >> 16) & 1)) >> 16);   // RNE
}
__device__ __forceinline__ u16 f2bf_hu(float f) {        // round-half-up: 2 VALU ops
  union { float f; uint32_t u; } c; c.f = f;
  return (u16)((c.u + 0x8000u) >> 16);
}
__device__ __forceinline__ float bf2f(u16 h) {
  union { uint32_t u; float f; } c; c.u = ((uint32_t)h) << 16;
  return c.f;
}

// XOR swizzle for LDS rows of 32 16B-units (512B rows)
__device__ __forceinline__ int swz32(int u, int row) {
  return (u & 24) | ((u & 7) ^ (row & 7));
}

__device__ __forceinline__ f32x4 mfma16(short8 a, short8 b, f32x4 c) {
  return __builtin_amdgcn_mfma_f32_16x16x32_bf16(a, b, c, 0, 0, 0);
}

// async global->LDS, 16B per lane; LDS dest is wave-uniform base + lane*16
__device__ __forceinline__ void gl_lds16(const u16* g, u16* l) {
  __builtin_amdgcn_global_load_lds(
      (const __attribute__((address_space(1))) uint32_t*)g,
      (__attribute__((address_space(3))) uint32_t*)l, 16, 0, 0);
}

// ---------------- kernel 1: fp32 -> hi/lo bf16 split ----------------
__global__ __launch_bounds__(256) void k_convert(
    const float* __restrict__ x1, const float* __restrict__ x2, const float* __restrict__ x3,
    const float* __restrict__ wq, const float* __restrict__ wk, const float* __restrict__ wv,
    u16* __restrict__ wsu) {
  int b = blockIdx.x;
  const float* src; u16 *dh, *dl; int bl;
  if (b < 1024)      { src = x1; dh = wsu + XH0; dl = wsu + XL0; bl = b; }
  else if (b < 2048) { src = x2; dh = wsu + XH1; dl = wsu + XL1; bl = b - 1024; }
  else if (b < 3072) { src = x3; dh = wsu + XH2; dl = wsu + XL2; bl = b - 2048; }
  else if (b < 3104) { src = wq; dh = wsu + WQH; dl = wsu + WQL; bl = b - 3072; }
  else if (b < 3136) { src = wk; dh = wsu + WKH; dl = wsu + WKL; bl = b - 3104; }
  else               { src = wv; dh = wsu + WVH; dl = wsu + WVL; bl = b - 3136; }
  int i = (bl * 256 + threadIdx.x) * 8;
  f32x4 a = *(const f32x4*)(src + i);
  f32x4 c = *(const f32x4*)(src + i + 4);
  short8 rh, rl;
  float v[8] = {a[0], a[1], a[2], a[3], c[0], c[1], c[2], c[3]};
#pragma unroll
  for (int j = 0; j < 8; j++) {
    u16 h = f2bf(v[j]);
    rh[j] = (short)h;
    rl[j] = (short)f2bf(v[j] - bf2f(h));
  }
  *(short8*)(dh + i) = rh;
  *(short8*)(dl + i) = rl;
}

// ---------------- kernel 2: QKV projection v3 — A-stationary ----------------
// NT gemm, 3-term hi/lo. Each block owns 32 A-rows (staged ONCE in 32 KB LDS)
// and sweeps the full 256-col output strip (4 col-iters x 4 waves x 16 cols).
// B fragments direct from global (contiguous 16B; W L2-resident, x3 L2/L3-hot).
// Kills the 8x redundant A re-staging of the 64x32-tile version (~250 MB -> 18 MB).
// grid: 768 = 3 mats x 256 strips.
__global__ __launch_bounds__(256) void k_qkv(
    u16* __restrict__ wsu,
    const float* __restrict__ bq, const float* __restrict__ bk, const float* __restrict__ bv) {
  __shared__ u16 sAh[32 * 256];   // 16 KB
  __shared__ u16 sAl[32 * 256];   // 16 KB
  int bx = blockIdx.x;
  int mid = bx >> 8;
  int t = bx & 255;
  const u16 *Ah, *Al, *Bh, *Bl; u16 *O; const float* bias;
  int rowA0, col0, ldO, biasRow;
  if (mid == 0) {
    Ah = wsu + XH0; Al = wsu + XL0; Bh = wsu + WQH; Bl = wsu + WQL;
    O = wsu + QH; bias = bq; biasRow = 0; ldO = 256;
    rowA0 = t * 32; col0 = 0;
  } else if (mid == 1) {
    Ah = wsu + XH1; Al = wsu + XL1; Bh = wsu + WKH; Bl = wsu + WKL;
    O = wsu + KH; bias = bk; biasRow = 0; ldO = 256;
    rowA0 = t * 32; col0 = 0;
  } else {
    Ah = wsu + WVH; Al = wsu + WVL; Bh = wsu + XH2; Bl = wsu + XL2;
    O = wsu + VTB; bias = bv; biasRow = 1; ldO = 8192;
    rowA0 = (t & 7) * 32; col0 = (t >> 3) * 256;
  }

  int tid = threadIdx.x;
#pragma unroll
  for (int i = 0; i < 4; i++) {            // stage A hi/lo: 32 rows x 32 units each
    int L = i * 256 + tid;
    int row = L >> 5, u = L & 31;
    short8 vh = *(const short8*)(Ah + (size_t)(rowA0 + row) * 256 + u * 8);
    short8 vl = *(const short8*)(Al + (size_t)(rowA0 + row) * 256 + u * 8);
    *(short8*)(&sAh[row * 256 + swz32(u, row) * 8]) = vh;
    *(short8*)(&sAl[row * 256 + swz32(u, row) * 8]) = vl;
  }
  __syncthreads();

  int lane = tid & 63, wave = tid >> 6;
  int n = lane & 15, quad = lane >> 4;

#pragma unroll 1
  for (int itc = 0; itc < 4; itc++) {
    int colg = col0 + itc * 64 + wave * 16 + n;
    const u16* pBh = Bh + (size_t)colg * 256 + quad * 8;
    const u16* pBl = Bl + (size_t)colg * 256 + quad * 8;
    f32x4 acc0 = {0.f,0.f,0.f,0.f}, acc1 = {0.f,0.f,0.f,0.f};
#pragma unroll
    for (int kk = 0; kk < 8; kk++) {
      int su = swz32(kk * 4 + quad, n) * 8;     // n and n+16 share (row&7) -> same su
      short8 a0h = *(const short8*)(&sAh[n * 256 + su]);
      short8 a1h = *(const short8*)(&sAh[(n + 16) * 256 + su]);
      short8 a0l = *(const short8*)(&sAl[n * 256 + su]);
      short8 a1l = *(const short8*)(&sAl[(n + 16) * 256 + su]);
      short8 bh  = *(const short8*)(pBh + kk * 32);
      short8 bl  = *(const short8*)(pBl + kk * 32);
      acc0 = mfma16(a0h, bh, acc0);
      acc1 = mfma16(a1h, bh, acc1);
      acc0 = mfma16(a0h, bl, acc0);
      acc1 = mfma16(a1h, bl, acc1);
      acc0 = mfma16(a0l, bh, acc0);
      acc1 = mfma16(a1l, bh, acc1);
    }
    float bcol = biasRow ? 0.0f : bias[colg];
#pragma unroll
    for (int mt = 0; mt < 2; mt++) {
      f32x4 acc = mt ? acc1 : acc0;
#pragma unroll
      for (int r = 0; r < 4; r++) {
        int rowg = rowA0 + mt * 16 + quad * 4 + r;
        float bb = biasRow ? bias[rowg] : bcol;
        O[(size_t)rowg * ldO + colg] = f2bf(acc[r] + bb);
      }
    }
  }
}

// ---------------- kernel 3: flash attention (R4 structure, verbatim) ----------------
// grid: 512 = 64 q-blocks x 8 key-splits; 4 waves x 32 q-rows each.
// Double-buffered K/V via gl_lds16 (no VGPR staging), one barrier/iter,
// fixed-base softmax. Per-iter address recompute — adding persistent pointer
// state here caused spills twice (R6, R7); do not "optimize" this again.
__global__ __launch_bounds__(256, 2) void k_flash(
    const u16* __restrict__ wsu, u16* __restrict__ opart, float* __restrict__ wsf) {
  __shared__ u16 sK[2][32 * 256];    // 2 x 16 KB
  __shared__ u16 sV[2][256 * 32];    // 2 x 16 KB
  __shared__ u16 sP[4 * 32 * 40];    // 10 KB: per-wave 32x32 P, stride 40

  int qb = blockIdx.x >> 3, sp = blockIdx.x & 7;   // split -> XCD pinning
  int tid = threadIdx.x, lane = tid & 63, wave = tid >> 6;
  int n = lane & 15, quad = lane >> 4;
  const u16* Qp = wsu + QH;
  const u16* Kp = wsu + KH;
  const u16* Vp = wsu + VTB;

  // Q fragments (A-layout) for 2 m-tiles: 64 VGPR
  short8 qf[2][8];
  int rowQ0 = qb * 128 + wave * 32 + n;
#pragma unroll
  for (int mt = 0; mt < 2; mt++)
#pragma unroll
    for (int kk = 0; kk < 8; kk++)
      qf[mt][kk] = *(const short8*)(Qp + (size_t)(rowQ0 + mt * 16) * 256 + kk * 32 + quad * 8);

  // staging lane geometry
  int krow_base = wave * 2 + (lane >> 5);                  // K row = i*8 + krow_base
  int kgu = (lane & 24) | ((lane & 7) ^ (krow_base & 7));  // inverse-swizzled source unit
  int vd_base = wave * 16 + (lane >> 2);                   // V d = i*64 + vd_base
  int vgu = (lane & 3) ^ ((lane >> 3) & 3);

  int key00 = sp * 1024;

  // preload tile 0 into buffer 0
#pragma unroll
  for (int i = 0; i < 4; i++) {
    gl_lds16(Kp + (size_t)(key00 + i * 8 + krow_base) * 256 + kgu * 8,
             &sK[0][i * 2048 + wave * 512]);
    gl_lds16(Vp + (size_t)(i * 64 + vd_base) * 8192 + key00 + vgu * 8,
             &sV[0][i * 2048 + wave * 512]);
  }

  f32x4 o[2][16];
#pragma unroll
  for (int mt = 0; mt < 2; mt++)
#pragma unroll
    for (int nt = 0; nt < 16; nt++) { o[mt][nt][0]=0.f; o[mt][nt][1]=0.f; o[mt][nt][2]=0.f; o[mt][nt][3]=0.f; }
  float negm0L[8], lcur[8];
#pragma unroll
  for (int j = 0; j < 8; j++) { negm0L[j] = 0.f; lcur[j] = 0.f; }

  for (int it = 0; it < 32; it++) {
    __syncthreads();   // drains vmcnt: buf[cur] loads complete; all waves done with buf[cur^1]
    int cur = it & 1;
    if (it + 1 < 32) {
      int k1 = key00 + (it + 1) * 32;
#pragma unroll
      for (int i = 0; i < 4; i++) {
        gl_lds16(Kp + (size_t)(k1 + i * 8 + krow_base) * 256 + kgu * 8,
                 &sK[cur ^ 1][i * 2048 + wave * 512]);
        gl_lds16(Vp + (size_t)(i * 64 + vd_base) * 8192 + k1 + vgu * 8,
                 &sV[cur ^ 1][i * 2048 + wave * 512]);
      }
    }

    // S = Q K^T: 2 m-tiles x 2 n-tiles x 8 ksteps = 32 MFMA
    f32x4 s00={0.f,0.f,0.f,0.f}, s01={0.f,0.f,0.f,0.f};
    f32x4 s10={0.f,0.f,0.f,0.f}, s11={0.f,0.f,0.f,0.f};
#pragma unroll
    for (int kk = 0; kk < 8; kk++) {
      int su = swz32(kk * 4 + quad, n) * 8;       // n and n+16 share (row&7) -> same su
      short8 b0 = *(const short8*)(&sK[cur][n * 256 + su]);
      short8 b1 = *(const short8*)(&sK[cur][(n + 16) * 256 + su]);
      s00 = mfma16(qf[0][kk], b0, s00);
      s01 = mfma16(qf[0][kk], b1, s01);
      s10 = mfma16(qf[1][kk], b0, s10);
      s11 = mfma16(qf[1][kk], b1, s11);
    }

    // fixed softmax base from first tile (no online rescale; logits bounded)
    if (it == 0) {
#pragma unroll
      for (int mt = 0; mt < 2; mt++)
#pragma unroll
        for (int r = 0; r < 4; r++) {
          float v = mt ? fmaxf(s10[r], s11[r]) : fmaxf(s00[r], s01[r]);
          v = fmaxf(v, __shfl_xor(v, 1));
          v = fmaxf(v, __shfl_xor(v, 2));
          v = fmaxf(v, __shfl_xor(v, 4));
          v = fmaxf(v, __shfl_xor(v, 8));
          negm0L[mt * 4 + r] = -v * LOG2E;
        }
    }

    // p = exp2(s*log2e + negm0), clamped; accumulate l; pack to LDS (C->A transform)
    u16* myP = &sP[wave * 1280];
#pragma unroll
    for (int mt = 0; mt < 2; mt++)
#pragma unroll
      for (int r = 0; r < 4; r++) {
        int j = mt * 4 + r;
        float sv0 = mt ? s10[r] : s00[r];
        float sv1 = mt ? s11[r] : s01[r];
        float x0 = fminf(fmaf(sv0, LOG2E, negm0L[j]), 110.f);
        float x1 = fminf(fmaf(sv1, LOG2E, negm0L[j]), 110.f);
        float p0 = exp2f(x0);
        float p1 = exp2f(x1);
        lcur[j] += p0 + p1;
        int row = mt * 16 + quad * 4 + r;
        myP[row * 40 + n] = f2bf_hu(p0);
        myP[row * 40 + 16 + n] = f2bf_hu(p1);
      }

    // PV: O[32 x 256] += P[32 x 32] @ V[32 x 256]
    u16* myP2 = &sP[wave * 1280];
    short8 pa0 = *(const short8*)(&myP2[n * 40 + quad * 8]);
    short8 pa1 = *(const short8*)(&myP2[(16 + n) * 40 + quad * 8]);
#pragma unroll
    for (int nt = 0; nt < 16; nt++) {
      int d = nt * 16 + n;
      short8 vb = *(const short8*)(&sV[cur][d * 32 + (quad ^ ((n >> 1) & 3)) * 8]);
      o[0][nt] = mfma16(pa0, vb, o[0][nt]);
      o[1][nt] = mfma16(pa1, vb, o[1][nt]);
    }
  }

  // reduce l across the 16 lanes sharing rows
#pragma unroll
  for (int j = 0; j < 8; j++) {
    float v = lcur[j];
    v += __shfl_xor(v, 1); v += __shfl_xor(v, 2);
    v += __shfl_xor(v, 4); v += __shfl_xor(v, 8);
    lcur[j] = v;
  }

  // store bf16 unnormalized partials + stats
  u16* op = opart + (size_t)sp * (NT * DH);
  int rowb = qb * 128 + wave * 32;
#pragma unroll
  for (int mt = 0; mt < 2; mt++)
#pragma unroll
    for (int nt = 0; nt < 16; nt++)
#pragma unroll
      for (int r = 0; r < 4; r++) {
        int row = rowb + mt * 16 + quad * 4 + r;
        op[(size_t)row * 256 + nt * 16 + n] = f2bf(o[mt][nt][r]);
      }
  if (n == 0) {
#pragma unroll
    for (int j = 0; j < 8; j++) {
      int row = rowb + (j >> 2) * 16 + quad * 4 + (j & 3);
      wsf[MPART_F + sp * NT + row] = negm0L[j] * -0.6931471805599453f;
      wsf[LPART_F + sp * NT + row] = lcur[j];
    }
  }
}

// ---------------- kernel 4: combine 8 splits ----------------
__global__ __launch_bounds__(256) void k_combine(
    const u16* __restrict__ opart, const float* __restrict__ wsf, float* __restrict__ out) {
  int gid = blockIdx.x * 256 + threadIdx.x;
  int row = gid >> 6, cg = gid & 63;
  float m[8], l[8];
#pragma unroll
  for (int s = 0; s < 8; s++) {
    m[s] = wsf[MPART_F + s * NT + row];
    l[s] = wsf[LPART_F + s * NT + row];
  }
  float ms = m[0];
#pragma unroll
  for (int s = 1; s < 8; s++) ms = fmaxf(ms, m[s]);
  float denom = 0.f;
  float acc[4] = {0.f, 0.f, 0.f, 0.f};
#pragma unroll
  for (int s = 0; s < 8; s++) {
    float w = exp2f((m[s] - ms) * LOG2E);
    denom += w * l[s];
    const u16* pp = opart + ((size_t)s * NT + row) * 256 + cg * 4;
    uint2 v = *(const uint2*)pp;
    acc[0] += w * bf2f((u16)(v.x & 0xffff));
    acc[1] += w * bf2f((u16)(v.x >> 16));
    acc[2] += w * bf2f((u16)(v.y & 0xffff));
    acc[3] += w * bf2f((u16)(v.y >> 16));
  }
  float inv = 1.0f / denom;
  f32x4 r = {acc[0] * inv, acc[1] * inv, acc[2] * inv, acc[3] * inv};
  *(f32x4*)(out + (size_t)row * 256 + cg * 4) = r;
}

extern "C" void kernel_launch(void* const* d_in, const int* in_sizes, int n_in,
                              void* d_out, int out_size, void* d_ws, size_t ws_size,
                              hipStream_t stream) {
  const float* x1 = (const float*)d_in[0];
  const float* x2 = (const float*)d_in[1];
  const float* x3 = (const float*)d_in[2];
  const float* Wq = (const float*)d_in[3];
  const float* bq = (const float*)d_in[4];
  const float* Wk = (const float*)d_in[5];
  const float* bk = (const float*)d_in[6];
  const float* Wv = (const float*)d_in[7];
  const float* bv = (const float*)d_in[8];
  u16* wsu = (u16*)d_ws;
  float* wsf = (float*)d_ws;
  float* out = (float*)d_out;

  k_convert<<<dim3(3168), dim3(256), 0, stream>>>(x1, x2, x3, Wq, Wk, Wv, wsu);
  k_qkv<<<dim3(768), dim3(256), 0, stream>>>(wsu, bq, bk, bv);
  k_flash<<<dim3(512), dim3(256), 0, stream>>>(wsu, wsu + OPARTB, wsf);
  k_combine<<<dim3(2048), dim3(256), 0, stream>>>(wsu + OPARTB, wsf, out);
}